// Round 18
// baseline (1012.949 us; speedup 1.0000x reference)
//
#include <hip/hip_runtime.h>
#include <hip/hip_bf16.h>

typedef __attribute__((ext_vector_type(8))) short bf16x8;
typedef __attribute__((ext_vector_type(4))) float f32x4;

#define DEV __device__ __forceinline__

static constexpr int Bn   = 64;
static constexpr int Hs   = 84;
static constexpr int HP   = 86;
static constexpr int C1c  = 128;
static constexpr int C2c  = 256;
static constexpr int NPOS = Hs * Hs;       // 7056
static constexpr float EPSf = 1e-5f;

DEV __hip_bfloat16 f2b(float v) { return __float2bfloat16(v); }

// async global(16B/lane) -> LDS (wave-uniform base + lane*16)
DEV void gload16(const void* g, void* l) {
    __builtin_amdgcn_global_load_lds(
        (const __attribute__((address_space(1))) void*)g,
        (__attribute__((address_space(3))) void*)l, 16, 0, 0);
}

// ---------------- conv1: 3->128 direct conv + BN + ReLU, f32 in -> padded NHWC bf16 (one chunk) ----------------
__global__ __launch_bounds__(128) void conv1_k(
    const float* __restrict__ x,   // chunk base: [chb,3,84,84] f32
    const float* __restrict__ w,  const float* __restrict__ cb,
    const float* __restrict__ g,  const float* __restrict__ be,
    const float* __restrict__ mm, const float* __restrict__ vv,
    __hip_bfloat16* __restrict__ h1)        // [chb,86,86,128]
{
    __shared__ float xin[3][3][HP];
    int bi = blockIdx.x;
    int b = bi / Hs, y = bi % Hs;
    int t = threadIdx.x;

    for (int idx = t; idx < 3 * 3 * HP; idx += 128) {
        int ci = idx / (3 * HP);
        int r  = idx % (3 * HP);
        int dy = r / HP;
        int xx = r % HP;
        int iy = y + dy - 1;
        int ix = xx - 1;
        float v = 0.f;
        if (iy >= 0 && iy < Hs && ix >= 0 && ix < Hs)
            v = x[((size_t)(b * 3 + ci) * Hs + iy) * Hs + ix];
        xin[ci][dy][xx] = v;
    }
    int co = t;
    float wr[3][3][3];
    for (int ci = 0; ci < 3; ci++)
        for (int dy = 0; dy < 3; dy++)
            for (int dx = 0; dx < 3; dx++)
                wr[ci][dy][dx] = w[((co * 3 + ci) * 3 + dy) * 3 + dx];
    float scale = g[co] / sqrtf(vv[co] + EPSf);
    float bias  = (cb[co] - mm[co]) * scale + be[co];
    __syncthreads();

    for (int xp = 0; xp < Hs; xp++) {
        float acc = 0.f;
        #pragma unroll
        for (int ci = 0; ci < 3; ci++)
            #pragma unroll
            for (int dy = 0; dy < 3; dy++)
                #pragma unroll
                for (int dx = 0; dx < 3; dx++)
                    acc += xin[ci][dy][xp + dx] * wr[ci][dy][dx];
        float o = acc * scale + bias;
        o = o > 0.f ? o : 0.f;
        h1[((size_t)(b * HP + y + 1) * HP + (xp + 1)) * C1c + co] = f2b(o);
    }
}

// ---------------- zero the 1px halo of a padded NHWC chunk buffer ----------------
template <int C>
__global__ void halo_zero(__hip_bfloat16* __restrict__ h)
{
    int i = blockIdx.x;
    int b = i / 340, p = i % 340;
    int y, xx;
    if (p < 86)       { y = 0;  xx = p; }
    else if (p < 172) { y = 85; xx = p - 86; }
    else if (p < 256) { xx = 0; y = p - 172 + 1; }
    else              { xx = 85; y = p - 256 + 1; }
    h[((size_t)(b * HP + y) * HP + xx) * C + threadIdx.x] = f2b(0.f);
}

// ---------------- repack conv weights OIHW f32 -> [K/32][256][32] bf16 (k = tap*CIN + ci) ----------------
template <int CIN>
__global__ void prep_w(const float* __restrict__ w, __hip_bfloat16* __restrict__ wm)
{
    int e  = blockIdx.x * 256 + threadIdx.x;   // over (9*CIN) * 256
    int k  = e >> 8;
    int co = e & 255;
    int tap = k / CIN;
    int ci  = k % CIN;
    int ty = tap / 3, tx = tap % 3;
    wm[(size_t)(k >> 5) * 8192 + co * 32 + (k & 31)] =
        f2b(w[((size_t)(co * CIN + ci) * 3 + ty) * 3 + tx]);
}

// ---------------- per-channel BN fold: sb[0:256]=scale, sb[256:512]=bias ----------------
__global__ void prep_sb(const float* __restrict__ cb, const float* __restrict__ g,
                        const float* __restrict__ be, const float* __restrict__ mm,
                        const float* __restrict__ vv, float* __restrict__ sb)
{
    int co = threadIdx.x;
    float s = g[co] / sqrtf(vv[co] + EPSf);
    sb[co] = s;
    sb[256 + co] = (cb[co] - mm[co]) * s + be[co];
}

__global__ void zero_f32(float* __restrict__ p)
{
    p[blockIdx.x * 256 + threadIdx.x] = 0.f;
}

// ---------------- 256x256 B-from-L2 pipelined implicit-GEMM conv (3x3 SAME) ----------------
// BM=256, BN=256, BK=64; 512 thr / 8 waves (2M x 4N, wave 128x64).
// A: double-buffered LDS (2 x 32 KB), global_load_lds staging (R13 path).
// B: DIRECT per-lane global_load_dwordx4 from the L2-resident repacked weight
//    matrix into registers, prefetched one kh-phase ahead (static bvA/bvB
//    double-buffer). This removes B from the LDS pipe entirely: per K-tile
//    LDS traffic drops 256 KB -> 160 KB (< MFMA 2065 cyc) — attacks the
//    measured LDS/MFMA alternation floor (R13-R17).
// Sync: ONE vmcnt(0)+barrier per K-tile (drains prev-phase A-stages + B
// prefetch exactly); P1 has no barrier — compiler inserts counted vmcnt /
// lgkmcnt for register loads; sched_barrier(0) pins load-issue before MFMA.
// LDS per buffer: A_kh0 @0, A_kh1 @16K; 64B rows, involution swizzle
// (0 conflicts R11-R17). kb-outer/tap-inner. grid.x = chb*NPOS/256, block=512.
template <int CIN, bool POOL>
__global__ __launch_bounds__(512, 2) void conv_igemm(
    const __hip_bfloat16* __restrict__ in, const __hip_bfloat16* __restrict__ wgt,
    const float* __restrict__ sb, __hip_bfloat16* __restrict__ out, float* __restrict__ pool)
{
    constexpr int KB = CIN / 32;
    constexpr int NK = 9 * KB / 2;             // K-tiles of 64 (18 or 36)
    constexpr unsigned BUFSZ = 32768u;         // 32 KB per A buffer
    __shared__ __align__(16) char lds[2 * 32768];
    __shared__ float pl[512];

    int t = threadIdx.x;
    int l = t & 63, w = t >> 6;                // 8 waves
    int lidx = l & 15, lg = l >> 4;
    int wm = w >> 2, wn = w & 3;               // wave tile: rows wm*128.., cols wn*64..

    // bijective XCD-aware swizzle (m204)
    int nwg  = (int)gridDim.x;
    int orig = (int)blockIdx.x;
    int xcd = orig & 7, idx = orig >> 3;
    int q = nwg >> 3, r = nwg & 7;
    int bx = (xcd < r ? xcd * (q + 1) : r * (q + 1) + (xcd - r) * q) + idx;
    int m0 = bx * 256;

    // ---- A staging lane sources: lane t stages rows (t>>2) and (t>>2)+128, PRE-SWIZZLED seg ----
    int seg  = (t & 3) ^ ((t >> 3) & 3);       // involution w/ row bits 1-2 (row = t>>2)
    int srow = t >> 2;                         // 0..127
    const __hip_bfloat16 *pA0, *pA1;
    {
        int gm = m0 + srow;
        int b0 = gm / NPOS; int r0 = gm - b0 * NPOS;
        int y0 = r0 / Hs;   int x0 = r0 - y0 * Hs;
        pA0 = in + ((size_t)(b0 * HP + y0) * HP + x0) * CIN + seg * 8;
        gm = m0 + 128 + srow;
        b0 = gm / NPOS; r0 = gm - b0 * NPOS;
        y0 = r0 / Hs;   x0 = r0 - y0 * Hs;
        pA1 = in + ((size_t)(b0 * HP + y0) * HP + x0) * CIN + seg * 8;
    }

    // ---- B direct-load base: lane needs wgt[kbg*8192 + co*32 + lg*8], 16B contig ----
    const __hip_bfloat16* pBF = wgt + (size_t)((wn * 64 + lidx) * 32 + lg * 8);

    // ---- A frag ds_read byte offsets (within one 32 KB buffer, swizzled) ----
    int swz = (lidx >> 1) & 3;
    unsigned aRd[8][2];
    #pragma unroll
    for (int mf = 0; mf < 8; mf++)
        #pragma unroll
        for (int kh = 0; kh < 2; kh++)
            aRd[mf][kh] = (unsigned)(kh * 16384 + (wm * 128 + mf * 16 + lidx) * 64 + ((lg ^ swz) * 16));

    f32x4 acc[8][4];
    #pragma unroll
    for (int i = 0; i < 8; i++)
        #pragma unroll
        for (int j = 0; j < 4; j++)
            acc[i][j] = (f32x4){0.f, 0.f, 0.f, 0.f};
    if (POOL) pl[t] = 0.f;

    // sub-step s -> (kb = s/9 OUTER, tap = s%9 INNER): L2 locality
    auto AOFF = [&](int s) -> size_t {
        int kb = s / 9, tap = s - kb * 9;
        int ty = tap / 3, tx = tap - ty * 3;
        return (size_t)(ty * HP + tx) * CIN + kb * 32;
    };
    auto BOFF = [&](int s) -> size_t {
        int kb = s / 9, tap = s - kb * 9;
        return (size_t)(tap * KB + kb) * 8192;
    };
    // stage A kh-half of K-tile kt2 into buffer base bb (2 gloads = 16 KB)
    auto ISSUE_A = [&](int kt2, int kh, unsigned bb) {
        int s = 2 * kt2 + kh;
        size_t ao = AOFF(s);
        unsigned ap = bb + (unsigned)(kh * 16384) + (unsigned)(w * 1024);
        gload16(pA0 + ao, lds + ap);
        gload16(pA1 + ao, lds + ap + 8192);
    };

    // prologue: stage A of K-tile 0 (both halves); preload B for phase 0
    ISSUE_A(0, 0, 0u);
    ISSUE_A(0, 1, 0u);
    bf16x8 bvA[4], bvB[4];
    {
        size_t bo = BOFF(0);
        #pragma unroll
        for (int nf = 0; nf < 4; nf++)
            bvA[nf] = *(const bf16x8*)(pBF + bo + nf * 512);
    }

    for (int kt = 0; kt < NK; ++kt) {
        unsigned cb = (kt & 1) ? BUFSZ : 0u;
        unsigned nb = (kt & 1) ? 0u : BUFSZ;
        bool more = (kt + 1) < NK;

        // ===== P0 (kh0): single sync point of the K-tile =====
        asm volatile("s_waitcnt vmcnt(0)" ::: "memory");  // A(kt) staged + B(P0) loaded
        __builtin_amdgcn_s_barrier();                      // publish A(kt) cross-wave
        asm volatile("" ::: "memory");

        {
            bf16x8 av[8];
            #pragma unroll
            for (int mf = 0; mf < 8; mf++)
                av[mf] = *(const bf16x8*)(lds + cb + aRd[mf][0]);
            // prefetch B for P1
            size_t bo1 = BOFF(2 * kt + 1);
            #pragma unroll
            for (int nf = 0; nf < 4; nf++)
                bvB[nf] = *(const bf16x8*)(pBF + bo1 + nf * 512);
            if (more) ISSUE_A(kt + 1, 0, nb);
            __builtin_amdgcn_sched_barrier(0);   // loads issued before MFMA
            __builtin_amdgcn_s_setprio(1);
            #pragma unroll
            for (int mf = 0; mf < 8; mf++)
                #pragma unroll
                for (int nf = 0; nf < 4; nf++)
                    acc[mf][nf] = __builtin_amdgcn_mfma_f32_16x16x32_bf16(
                        av[mf], bvA[nf], acc[mf][nf], 0, 0, 0);
            __builtin_amdgcn_s_setprio(0);
        }

        // ===== P1 (kh1): no barrier (A both halves published at P0) =====
        {
            bf16x8 av[8];
            #pragma unroll
            for (int mf = 0; mf < 8; mf++)
                av[mf] = *(const bf16x8*)(lds + cb + aRd[mf][1]);
            if (more) {
                // prefetch B for next tile's P0
                size_t bo2 = BOFF(2 * kt + 2);
                #pragma unroll
                for (int nf = 0; nf < 4; nf++)
                    bvA[nf] = *(const bf16x8*)(pBF + bo2 + nf * 512);
                ISSUE_A(kt + 1, 1, nb);
            }
            __builtin_amdgcn_sched_barrier(0);
            __builtin_amdgcn_s_setprio(1);
            #pragma unroll
            for (int mf = 0; mf < 8; mf++)
                #pragma unroll
                for (int nf = 0; nf < 4; nf++)
                    acc[mf][nf] = __builtin_amdgcn_mfma_f32_16x16x32_bf16(
                        av[mf], bvB[nf], acc[mf][nf], 0, 0, 0);
            __builtin_amdgcn_s_setprio(0);
        }
    }

    // ---- epilogue ----
    float sc[4], bi2[4];
    #pragma unroll
    for (int nf = 0; nf < 4; nf++) {
        int cn = wn * 64 + nf * 16 + lidx;
        sc[nf]  = sb[cn];
        bi2[nf] = sb[256 + cn];
    }

    if (!POOL) {
        #pragma unroll
        for (int mf = 0; mf < 8; mf++) {
            #pragma unroll
            for (int r2 = 0; r2 < 4; r2++) {
                int row = wm * 128 + mf * 16 + lg * 4 + r2;
                int gm2 = m0 + row;
                int b2  = gm2 / NPOS;
                int rm2 = gm2 - b2 * NPOS;
                int y2  = rm2 / Hs;
                int x2  = rm2 - y2 * Hs;
                size_t ob = ((size_t)(b2 * HP + y2 + 1) * HP + (x2 + 1)) * 256;
                #pragma unroll
                for (int nf = 0; nf < 4; nf++) {
                    float v = acc[mf][nf][r2] * sc[nf] + bi2[nf];
                    v = v > 0.f ? v : 0.f;
                    out[ob + wn * 64 + nf * 16 + lidx] = f2b(v);
                }
            }
        }
    } else {
        int bs_lo   = m0 / NPOS;
        int row_lim = (bs_lo + 1) * NPOS - m0;  // rows >= row_lim belong to image bs_lo+1
        __builtin_amdgcn_s_barrier();            // pl[] init visible
        #pragma unroll
        for (int nf = 0; nf < 4; nf++) {
            float s0 = 0.f, s1 = 0.f;
            #pragma unroll
            for (int mf = 0; mf < 8; mf++)
                #pragma unroll
                for (int r2 = 0; r2 < 4; r2++) {
                    int row = wm * 128 + mf * 16 + lg * 4 + r2;
                    float v = acc[mf][nf][r2] * sc[nf] + bi2[nf];
                    v = v > 0.f ? v : 0.f;
                    if (row < row_lim) s0 += v; else s1 += v;
                }
            int cl = wn * 64 + nf * 16 + lidx;   // [0,256)
            atomicAdd(&pl[cl], s0);
            if (row_lim < 256) atomicAdd(&pl[256 + cl], s1);
        }
        __syncthreads();
        if (t < 256)
            atomicAdd(&pool[bs_lo * 256 + t], pl[t]);
        else if (row_lim < 256)
            atomicAdd(&pool[(bs_lo + 1) * 256 + (t - 256)], pl[t]);
    }
}

// ---------------- pool finalize: mean ----------------
__global__ void pool_div(const float* __restrict__ pool, float* __restrict__ h0)
{
    int i = blockIdx.x * 256 + threadIdx.x;
    h0[i] = pool[i] * (1.0f / (float)NPOS);
}

// ---------------- GCN attention: ew = softmax(leaky(p[row]+q[col]+ab)) over 256 edges ----------------
__global__ __launch_bounds__(256) void gcn_attn(
    const float* __restrict__ h, const float* __restrict__ aw,
    const float* __restrict__ ab, const int* __restrict__ ei,
    float* __restrict__ ew)
{
    __shared__ float p[64], q[64], red[256];
    int t = threadIdx.x;
    if (t < 64) {
        float pp = 0.f, qq = 0.f;
        for (int c = 0; c < 256; c++) {
            float hv = h[t * 256 + c];
            pp += hv * aw[c];
            qq += hv * aw[256 + c];
        }
        p[t] = pp; q[t] = qq;
    }
    __syncthreads();
    int r = ei[t], c = ei[256 + t];
    float s = p[r] + q[c] + ab[0];
    s = s >= 0.f ? s : 0.01f * s;
    red[t] = s;
    __syncthreads();
    for (int st = 128; st > 0; st >>= 1) {
        if (t < st) red[t] = fmaxf(red[t], red[t + st]);
        __syncthreads();
    }
    float mx = red[0];
    __syncthreads();
    float e = expf(s - mx);
    red[t] = e;
    __syncthreads();
    for (int st = 128; st > 0; st >>= 1) {
        if (t < st) red[t] += red[t + st];
        __syncthreads();
    }
    ew[t] = e / red[0];
}

// ---------------- GCN aggregate + linear + residual (+ReLU) ----------------
__global__ __launch_bounds__(256) void gcn_agg(
    const float* __restrict__ h, const float* __restrict__ ew, const int* __restrict__ ei,
    const float* __restrict__ lw, const float* __restrict__ lb,
    float* __restrict__ ho)
{
    __shared__ float agg[256];
    __shared__ float ewl[256];
    __shared__ int rl[256], cl[256];
    int n = blockIdx.x;
    int t = threadIdx.x;
    ewl[t] = ew[t];
    rl[t] = ei[t];
    cl[t] = ei[256 + t];
    __syncthreads();
    float a = 0.f;
    for (int e = 0; e < 256; e++)
        if (rl[e] == n) a += ewl[e] * h[cl[e] * 256 + t];
    agg[t] = a;
    __syncthreads();
    float o = 0.f;
    for (int c2 = 0; c2 < 256; c2++)
        o += agg[c2] * lw[t * 256 + c2];
    o += lb[t] + h[n * 256 + t];
    o = o > 0.f ? o : 0.f;
    ho[n * 256 + t] = o;
}

// ---------------- final fc: [64,256] @ [50,256]^T + b -> f32 out ----------------
__global__ void fc_k(const float* __restrict__ h, const float* __restrict__ fw,
                     const float* __restrict__ fb, float* __restrict__ out)
{
    int n = blockIdx.x;
    int t = threadIdx.x;
    if (t < 50) {
        float o = 0.f;
        for (int c = 0; c < 256; c++)
            o += h[n * 256 + c] * fw[t * 256 + c];
        o += fb[t];
        out[n * 50 + t] = o;
    }
}

extern "C" void kernel_launch(void* const* d_in, const int* in_sizes, int n_in,
                              void* d_out, int out_size, void* d_ws, size_t ws_size,
                              hipStream_t stream)
{
    (void)in_sizes; (void)n_in; (void)out_size;

    const float* X    = (const float*)d_in[0];
    const float* c1w  = (const float*)d_in[1];
    const float* c1b  = (const float*)d_in[2];
    const float* b1g  = (const float*)d_in[3];
    const float* b1b  = (const float*)d_in[4];
    const float* b1m  = (const float*)d_in[5];
    const float* b1v  = (const float*)d_in[6];
    const float* c2w  = (const float*)d_in[7];
    const float* c2b  = (const float*)d_in[8];
    const float* b2g  = (const float*)d_in[9];
    const float* b2b  = (const float*)d_in[10];
    const float* b2m  = (const float*)d_in[11];
    const float* b2v  = (const float*)d_in[12];
    const float* c3w  = (const float*)d_in[13];
    const float* c3b  = (const float*)d_in[14];
    const float* b3g  = (const float*)d_in[15];
    const float* b3b  = (const float*)d_in[16];
    const float* b3m  = (const float*)d_in[17];
    const float* b3v  = (const float*)d_in[18];
    const float* g1lw = (const float*)d_in[19];
    const float* g1lb = (const float*)d_in[20];
    const float* g1aw = (const float*)d_in[21];
    const float* g1ab = (const float*)d_in[22];
    const float* g2lw = (const float*)d_in[23];
    const float* g2lb = (const float*)d_in[24];
    const float* g2aw = (const float*)d_in[25];
    const float* g2ab = (const float*)d_in[26];
    const float* fcw  = (const float*)d_in[27];
    const float* fcb  = (const float*)d_in[28];
    const int*   EI   = (const int*)d_in[29];

    // runtime chunk size: largest of {64,32,16} that fits (chb*NPOS must be /256)
    size_t fixedB = 3000000;
    int chb = 16;
    if (ws_size >= (size_t)64 * 5680128 + fixedB)      chb = 64;
    else if (ws_size >= (size_t)32 * 5680128 + fixedB) chb = 32;
    int nchunks = Bn / chb;
    int mch = chb * NPOS;                  // positions per chunk (div by 256)

    char* p = (char*)d_ws;
    auto carve = [&](size_t bytes) {
        char* r = p;
        p += (bytes + 255) & ~(size_t)255;
        return r;
    };
    __hip_bfloat16* h1c = (__hip_bfloat16*)carve((size_t)chb * HP * HP * C1c * 2);
    __hip_bfloat16* h2c = (__hip_bfloat16*)carve((size_t)chb * HP * HP * C2c * 2);
    __hip_bfloat16* wm2 = (__hip_bfloat16*)carve((size_t)9 * C1c * 256 * 2);
    __hip_bfloat16* wm3 = (__hip_bfloat16*)carve((size_t)9 * C2c * 256 * 2);
    float* sb2  = (float*)carve(512 * 4);
    float* sb3  = (float*)carve(512 * 4);
    float* pool = (float*)carve(64 * 256 * 4);
    float* h0   = (float*)carve(64 * 256 * 4);
    float* hg1  = (float*)carve(64 * 256 * 4);
    float* hg2  = (float*)carve(64 * 256 * 4);
    float* ew1  = (float*)carve(256 * 4);
    float* ew2  = (float*)carve(256 * 4);

    // prep (independent of conv outputs); halos stay zero across chunks/replays
    halo_zero<C1c><<<dim3(chb * 340), dim3(C1c), 0, stream>>>(h1c);
    halo_zero<C2c><<<dim3(chb * 340), dim3(C2c), 0, stream>>>(h2c);
    prep_w<C1c><<<dim3(9 * C1c), dim3(256), 0, stream>>>(c2w, wm2);
    prep_w<C2c><<<dim3(9 * C2c), dim3(256), 0, stream>>>(c3w, wm3);
    prep_sb<<<dim3(1), dim3(256), 0, stream>>>(c2b, b2g, b2b, b2m, b2v, sb2);
    prep_sb<<<dim3(1), dim3(256), 0, stream>>>(c3b, b3g, b3b, b3m, b3v, sb3);
    zero_f32<<<dim3(64), dim3(256), 0, stream>>>(pool);

    // conv chain, chunked over batch (chb images per chunk)
    for (int ch = 0; ch < nchunks; ch++) {
        const float* xch = X + (size_t)ch * chb * 3 * NPOS;
        conv1_k<<<dim3(chb * Hs), dim3(C1c), 0, stream>>>(
            xch, c1w, c1b, b1g, b1b, b1m, b1v, h1c);
        conv_igemm<C1c, false><<<dim3(mch / 256), dim3(512), 0, stream>>>(
            h1c, wm2, sb2, h2c, nullptr);
        conv_igemm<C2c, true ><<<dim3(mch / 256), dim3(512), 0, stream>>>(
            h2c, wm3, sb3, nullptr, pool + (size_t)ch * chb * 256);
    }
    pool_div<<<dim3(64), dim3(256), 0, stream>>>(pool, h0);

    // GCN layers + fc
    gcn_attn<<<dim3(1), dim3(256), 0, stream>>>(h0, g1aw, g1ab, EI, ew1);
    gcn_agg<<<dim3(64), dim3(256), 0, stream>>>(h0, ew1, EI, g1lw, g1lb, hg1);
    gcn_attn<<<dim3(1), dim3(256), 0, stream>>>(hg1, g2aw, g2ab, EI, ew2);
    gcn_agg<<<dim3(64), dim3(256), 0, stream>>>(hg1, ew2, EI, g2lw, g2lb, hg2);
    fc_k<<<dim3(64), dim3(64), 0, stream>>>(hg2, fcw, fcb, (float*)d_out);
}

// Round 19
// 886.389 us; speedup vs baseline: 1.1428x; 1.1428x over previous
//
#include <hip/hip_runtime.h>
#include <hip/hip_bf16.h>

typedef __attribute__((ext_vector_type(8))) short bf16x8;
typedef __attribute__((ext_vector_type(4))) float f32x4;

#define DEV __device__ __forceinline__

static constexpr int Bn   = 64;
static constexpr int Hs   = 84;
static constexpr int HP   = 86;
static constexpr int C1c  = 128;
static constexpr int C2c  = 256;
static constexpr int NPOS = Hs * Hs;       // 7056
static constexpr float EPSf = 1e-5f;

DEV __hip_bfloat16 f2b(float v) { return __float2bfloat16(v); }

// async global(16B/lane) -> LDS (wave-uniform base + lane*16)
DEV void gload16(const void* g, void* l) {
    __builtin_amdgcn_global_load_lds(
        (const __attribute__((address_space(1))) void*)g,
        (__attribute__((address_space(3))) void*)l, 16, 0, 0);
}

// ---------------- conv1: 3->128 direct conv + BN + ReLU, f32 in -> padded NHWC bf16 (one chunk) ----------------
__global__ __launch_bounds__(128) void conv1_k(
    const float* __restrict__ x,   // chunk base: [chb,3,84,84] f32
    const float* __restrict__ w,  const float* __restrict__ cb,
    const float* __restrict__ g,  const float* __restrict__ be,
    const float* __restrict__ mm, const float* __restrict__ vv,
    __hip_bfloat16* __restrict__ h1)        // [chb,86,86,128]
{
    __shared__ float xin[3][3][HP];
    int bi = blockIdx.x;
    int b = bi / Hs, y = bi % Hs;
    int t = threadIdx.x;

    for (int idx = t; idx < 3 * 3 * HP; idx += 128) {
        int ci = idx / (3 * HP);
        int r  = idx % (3 * HP);
        int dy = r / HP;
        int xx = r % HP;
        int iy = y + dy - 1;
        int ix = xx - 1;
        float v = 0.f;
        if (iy >= 0 && iy < Hs && ix >= 0 && ix < Hs)
            v = x[((size_t)(b * 3 + ci) * Hs + iy) * Hs + ix];
        xin[ci][dy][xx] = v;
    }
    int co = t;
    float wr[3][3][3];
    for (int ci = 0; ci < 3; ci++)
        for (int dy = 0; dy < 3; dy++)
            for (int dx = 0; dx < 3; dx++)
                wr[ci][dy][dx] = w[((co * 3 + ci) * 3 + dy) * 3 + dx];
    float scale = g[co] / sqrtf(vv[co] + EPSf);
    float bias  = (cb[co] - mm[co]) * scale + be[co];
    __syncthreads();

    for (int xp = 0; xp < Hs; xp++) {
        float acc = 0.f;
        #pragma unroll
        for (int ci = 0; ci < 3; ci++)
            #pragma unroll
            for (int dy = 0; dy < 3; dy++)
                #pragma unroll
                for (int dx = 0; dx < 3; dx++)
                    acc += xin[ci][dy][xp + dx] * wr[ci][dy][dx];
        float o = acc * scale + bias;
        o = o > 0.f ? o : 0.f;
        h1[((size_t)(b * HP + y + 1) * HP + (xp + 1)) * C1c + co] = f2b(o);
    }
}

// ---------------- zero the 1px halo of a padded NHWC chunk buffer ----------------
template <int C>
__global__ void halo_zero(__hip_bfloat16* __restrict__ h)
{
    int i = blockIdx.x;
    int b = i / 340, p = i % 340;
    int y, xx;
    if (p < 86)       { y = 0;  xx = p; }
    else if (p < 172) { y = 85; xx = p - 86; }
    else if (p < 256) { xx = 0; y = p - 172 + 1; }
    else              { xx = 85; y = p - 256 + 1; }
    h[((size_t)(b * HP + y) * HP + xx) * C + threadIdx.x] = f2b(0.f);
}

// ---------------- repack conv weights OIHW f32 -> [K/32][256][32] bf16 (k = tap*CIN + ci) ----------------
template <int CIN>
__global__ void prep_w(const float* __restrict__ w, __hip_bfloat16* __restrict__ wm)
{
    int e  = blockIdx.x * 256 + threadIdx.x;   // over (9*CIN) * 256
    int k  = e >> 8;
    int co = e & 255;
    int tap = k / CIN;
    int ci  = k % CIN;
    int ty = tap / 3, tx = tap % 3;
    wm[(size_t)(k >> 5) * 8192 + co * 32 + (k & 31)] =
        f2b(w[((size_t)(co * CIN + ci) * 3 + ty) * 3 + tx]);
}

// ---------------- per-channel BN fold: sb[0:256]=scale, sb[256:512]=bias ----------------
__global__ void prep_sb(const float* __restrict__ cb, const float* __restrict__ g,
                        const float* __restrict__ be, const float* __restrict__ mm,
                        const float* __restrict__ vv, float* __restrict__ sb)
{
    int co = threadIdx.x;
    float s = g[co] / sqrtf(vv[co] + EPSf);
    sb[co] = s;
    sb[256 + co] = (cb[co] - mm[co]) * s + be[co];
}

__global__ void zero_f32(float* __restrict__ p)
{
    p[blockIdx.x * 256 + threadIdx.x] = 0.f;
}

// ---------------- 256x256 2-phase/K-tile pipelined implicit-GEMM conv (3x3 SAME) ----------------
// R13 base (measured best) with two micro-tweaks:
//  (1) bv reads issued BEFORE av reads -> first MFMA row needs only 5 reads,
//      remaining av[] stream in under compute (in-wave pipeline via counted lgkmcnt)
//  (2) setprio removed (T5 measured harmful in lockstep structures, m190)
// BM=256, BN=256, BK=64; 512 thr / 8 waves (2M x 4N, wave 128x64).
// Double-buffered LDS (2 x 64 KB), counted vmcnt(4), ONE barrier per kh-phase.
// LDS planes per buffer: A_kh0 @0, A_kh1 @16K, B_kh0 @32K, B_kh1 @48K; 64B rows,
// involution swizzle (0 conflicts). kb-outer/tap-inner.
// grid.x = chb*NPOS/256, block = 512.
template <int CIN, bool POOL>
__global__ __launch_bounds__(512, 2) void conv_igemm(
    const __hip_bfloat16* __restrict__ in, const __hip_bfloat16* __restrict__ wgt,
    const float* __restrict__ sb, __hip_bfloat16* __restrict__ out, float* __restrict__ pool)
{
    constexpr int KB = CIN / 32;
    constexpr int NK = 9 * KB / 2;             // K-tiles of 64 (18 or 36)
    constexpr unsigned BUFSZ = 65536u;         // 64 KB per buffer
    __shared__ __align__(16) char lds[2 * 65536];
    __shared__ float pl[512];

    int t = threadIdx.x;
    int l = t & 63, w = t >> 6;                // 8 waves
    int lidx = l & 15, lg = l >> 4;
    int wm = w >> 2, wn = w & 3;               // wave tile: rows wm*128.., cols wn*64..

    // bijective XCD-aware swizzle (m204)
    int nwg  = (int)gridDim.x;
    int orig = (int)blockIdx.x;
    int xcd = orig & 7, idx = orig >> 3;
    int q = nwg >> 3, r = nwg & 7;
    int bx = (xcd < r ? xcd * (q + 1) : r * (q + 1) + (xcd - r) * q) + idx;
    int m0 = bx * 256;

    // ---- staging lane sources: lane t stages rows (t>>2) and (t>>2)+128, PRE-SWIZZLED seg ----
    int seg  = (t & 3) ^ ((t >> 3) & 3);       // involution w/ row bits 1-2 (row = t>>2)
    int srow = t >> 2;                         // 0..127
    const __hip_bfloat16 *pA0, *pA1;
    {
        int gm = m0 + srow;
        int b0 = gm / NPOS; int r0 = gm - b0 * NPOS;
        int y0 = r0 / Hs;   int x0 = r0 - y0 * Hs;
        pA0 = in + ((size_t)(b0 * HP + y0) * HP + x0) * CIN + seg * 8;
        gm = m0 + 128 + srow;
        b0 = gm / NPOS; r0 = gm - b0 * NPOS;
        y0 = r0 / Hs;   x0 = r0 - y0 * Hs;
        pA1 = in + ((size_t)(b0 * HP + y0) * HP + x0) * CIN + seg * 8;
    }
    const __hip_bfloat16* pB0 = wgt + (size_t)srow * 32 + seg * 8;
    const __hip_bfloat16* pB1 = wgt + (size_t)(128 + srow) * 32 + seg * 8;

    // ---- frag ds_read byte offsets (within one 64 KB buffer, swizzled) ----
    int swz = (lidx >> 1) & 3;
    unsigned aRd[8][2], bRd[4][2];
    #pragma unroll
    for (int mf = 0; mf < 8; mf++)
        #pragma unroll
        for (int kh = 0; kh < 2; kh++)
            aRd[mf][kh] = (unsigned)(kh * 16384 + (wm * 128 + mf * 16 + lidx) * 64 + ((lg ^ swz) * 16));
    #pragma unroll
    for (int nf = 0; nf < 4; nf++)
        #pragma unroll
        for (int kh = 0; kh < 2; kh++)
            bRd[nf][kh] = (unsigned)(32768 + kh * 16384 + (wn * 64 + nf * 16 + lidx) * 64 + ((lg ^ swz) * 16));

    f32x4 acc[8][4];
    #pragma unroll
    for (int i = 0; i < 8; i++)
        #pragma unroll
        for (int j = 0; j < 4; j++)
            acc[i][j] = (f32x4){0.f, 0.f, 0.f, 0.f};
    if (POOL) pl[t] = 0.f;

    // sub-step s -> (kb = s/9 OUTER, tap = s%9 INNER): L2 locality (R6/R8 lesson)
    auto AOFF = [&](int s) -> size_t {
        int kb = s / 9, tap = s - kb * 9;
        int ty = tap / 3, tx = tap - ty * 3;
        return (size_t)(ty * HP + tx) * CIN + kb * 32;
    };
    auto BOFF = [&](int s) -> size_t {
        int kb = s / 9, tap = s - kb * 9;
        return (size_t)(tap * KB + kb) * 8192;
    };
    // stage kh-half of K-tile kt2 into buffer base bb (4 gloads = A 16KB + B 16KB)
    auto ISSUE = [&](int kt2, int kh, unsigned bb) {
        int s = 2 * kt2 + kh;
        size_t ao = AOFF(s), bo = BOFF(s);
        unsigned ap = bb + (unsigned)(kh * 16384) + (unsigned)(w * 1024);
        unsigned bp = bb + 32768u + (unsigned)(kh * 16384) + (unsigned)(w * 1024);
        gload16(pA0 + ao, lds + ap);
        gload16(pA1 + ao, lds + ap + 8192);
        gload16(pB0 + bo, lds + bp);
        gload16(pB1 + bo, lds + bp + 8192);
    };

    // prologue: stage both halves of K-tile 0 (8 loads in flight)
    ISSUE(0, 0, 0u);
    ISSUE(0, 1, 0u);

    for (int kt = 0; kt < NK; ++kt) {
        unsigned cb = (kt & 1) ? BUFSZ : 0u;
        unsigned nb = (kt & 1) ? 0u : BUFSZ;
        bool more = (kt + 1) < NK;

        #pragma unroll
        for (int kh = 0; kh < 2; ++kh) {
            // one vmcnt + one barrier per kh-phase
            if (kh == 0 || more) asm volatile("s_waitcnt vmcnt(4)" ::: "memory");
            else                 asm volatile("s_waitcnt vmcnt(0)" ::: "memory");
            __builtin_amdgcn_s_barrier();   // all waves' kh-half of tile kt landed
            asm volatile("" ::: "memory");

            // bv FIRST, then av: first MFMA row ready after 5 reads; av[1..7]
            // stream in under compute (compiler counted lgkmcnt)
            bf16x8 bv[4], av[8];
            #pragma unroll
            for (int nf = 0; nf < 4; nf++)
                bv[nf] = *(const bf16x8*)(lds + cb + bRd[nf][kh]);
            #pragma unroll
            for (int mf = 0; mf < 8; mf++)
                av[mf] = *(const bf16x8*)(lds + cb + aRd[mf][kh]);
            if (more) ISSUE(kt + 1, kh, nb);
            #pragma unroll
            for (int mf = 0; mf < 8; mf++)
                #pragma unroll
                for (int nf = 0; nf < 4; nf++)
                    acc[mf][nf] = __builtin_amdgcn_mfma_f32_16x16x32_bf16(
                        av[mf], bv[nf], acc[mf][nf], 0, 0, 0);
        }
    }

    // ---- epilogue ----
    float sc[4], bi2[4];
    #pragma unroll
    for (int nf = 0; nf < 4; nf++) {
        int cn = wn * 64 + nf * 16 + lidx;
        sc[nf]  = sb[cn];
        bi2[nf] = sb[256 + cn];
    }

    if (!POOL) {
        #pragma unroll
        for (int mf = 0; mf < 8; mf++) {
            #pragma unroll
            for (int r2 = 0; r2 < 4; r2++) {
                int row = wm * 128 + mf * 16 + lg * 4 + r2;
                int gm2 = m0 + row;
                int b2  = gm2 / NPOS;
                int rm2 = gm2 - b2 * NPOS;
                int y2  = rm2 / Hs;
                int x2  = rm2 - y2 * Hs;
                size_t ob = ((size_t)(b2 * HP + y2 + 1) * HP + (x2 + 1)) * 256;
                #pragma unroll
                for (int nf = 0; nf < 4; nf++) {
                    float v = acc[mf][nf][r2] * sc[nf] + bi2[nf];
                    v = v > 0.f ? v : 0.f;
                    out[ob + wn * 64 + nf * 16 + lidx] = f2b(v);
                }
            }
        }
    } else {
        int bs_lo   = m0 / NPOS;
        int row_lim = (bs_lo + 1) * NPOS - m0;  // rows >= row_lim belong to image bs_lo+1
        __builtin_amdgcn_s_barrier();            // pl[] init visible
        #pragma unroll
        for (int nf = 0; nf < 4; nf++) {
            float s0 = 0.f, s1 = 0.f;
            #pragma unroll
            for (int mf = 0; mf < 8; mf++)
                #pragma unroll
                for (int r2 = 0; r2 < 4; r2++) {
                    int row = wm * 128 + mf * 16 + lg * 4 + r2;
                    float v = acc[mf][nf][r2] * sc[nf] + bi2[nf];
                    v = v > 0.f ? v : 0.f;
                    if (row < row_lim) s0 += v; else s1 += v;
                }
            int cl = wn * 64 + nf * 16 + lidx;   // [0,256)
            atomicAdd(&pl[cl], s0);
            if (row_lim < 256) atomicAdd(&pl[256 + cl], s1);
        }
        __syncthreads();
        if (t < 256)
            atomicAdd(&pool[bs_lo * 256 + t], pl[t]);
        else if (row_lim < 256)
            atomicAdd(&pool[(bs_lo + 1) * 256 + (t - 256)], pl[t]);
    }
}

// ---------------- pool finalize: mean ----------------
__global__ void pool_div(const float* __restrict__ pool, float* __restrict__ h0)
{
    int i = blockIdx.x * 256 + threadIdx.x;
    h0[i] = pool[i] * (1.0f / (float)NPOS);
}

// ---------------- GCN attention: ew = softmax(leaky(p[row]+q[col]+ab)) over 256 edges ----------------
__global__ __launch_bounds__(256) void gcn_attn(
    const float* __restrict__ h, const float* __restrict__ aw,
    const float* __restrict__ ab, const int* __restrict__ ei,
    float* __restrict__ ew)
{
    __shared__ float p[64], q[64], red[256];
    int t = threadIdx.x;
    if (t < 64) {
        float pp = 0.f, qq = 0.f;
        for (int c = 0; c < 256; c++) {
            float hv = h[t * 256 + c];
            pp += hv * aw[c];
            qq += hv * aw[256 + c];
        }
        p[t] = pp; q[t] = qq;
    }
    __syncthreads();
    int r = ei[t], c = ei[256 + t];
    float s = p[r] + q[c] + ab[0];
    s = s >= 0.f ? s : 0.01f * s;
    red[t] = s;
    __syncthreads();
    for (int st = 128; st > 0; st >>= 1) {
        if (t < st) red[t] = fmaxf(red[t], red[t + st]);
        __syncthreads();
    }
    float mx = red[0];
    __syncthreads();
    float e = expf(s - mx);
    red[t] = e;
    __syncthreads();
    for (int st = 128; st > 0; st >>= 1) {
        if (t < st) red[t] += red[t + st];
        __syncthreads();
    }
    ew[t] = e / red[0];
}

// ---------------- GCN aggregate + linear + residual (+ReLU) ----------------
__global__ __launch_bounds__(256) void gcn_agg(
    const float* __restrict__ h, const float* __restrict__ ew, const int* __restrict__ ei,
    const float* __restrict__ lw, const float* __restrict__ lb,
    float* __restrict__ ho)
{
    __shared__ float agg[256];
    __shared__ float ewl[256];
    __shared__ int rl[256], cl[256];
    int n = blockIdx.x;
    int t = threadIdx.x;
    ewl[t] = ew[t];
    rl[t] = ei[t];
    cl[t] = ei[256 + t];
    __syncthreads();
    float a = 0.f;
    for (int e = 0; e < 256; e++)
        if (rl[e] == n) a += ewl[e] * h[cl[e] * 256 + t];
    agg[t] = a;
    __syncthreads();
    float o = 0.f;
    for (int c2 = 0; c2 < 256; c2++)
        o += agg[c2] * lw[t * 256 + c2];
    o += lb[t] + h[n * 256 + t];
    o = o > 0.f ? o : 0.f;
    ho[n * 256 + t] = o;
}

// ---------------- final fc: [64,256] @ [50,256]^T + b -> f32 out ----------------
__global__ void fc_k(const float* __restrict__ h, const float* __restrict__ fw,
                     const float* __restrict__ fb, float* __restrict__ out)
{
    int n = blockIdx.x;
    int t = threadIdx.x;
    if (t < 50) {
        float o = 0.f;
        for (int c = 0; c < 256; c++)
            o += h[n * 256 + c] * fw[t * 256 + c];
        o += fb[t];
        out[n * 50 + t] = o;
    }
}

extern "C" void kernel_launch(void* const* d_in, const int* in_sizes, int n_in,
                              void* d_out, int out_size, void* d_ws, size_t ws_size,
                              hipStream_t stream)
{
    (void)in_sizes; (void)n_in; (void)out_size;

    const float* X    = (const float*)d_in[0];
    const float* c1w  = (const float*)d_in[1];
    const float* c1b  = (const float*)d_in[2];
    const float* b1g  = (const float*)d_in[3];
    const float* b1b  = (const float*)d_in[4];
    const float* b1m  = (const float*)d_in[5];
    const float* b1v  = (const float*)d_in[6];
    const float* c2w  = (const float*)d_in[7];
    const float* c2b  = (const float*)d_in[8];
    const float* b2g  = (const float*)d_in[9];
    const float* b2b  = (const float*)d_in[10];
    const float* b2m  = (const float*)d_in[11];
    const float* b2v  = (const float*)d_in[12];
    const float* c3w  = (const float*)d_in[13];
    const float* c3b  = (const float*)d_in[14];
    const float* b3g  = (const float*)d_in[15];
    const float* b3b  = (const float*)d_in[16];
    const float* b3m  = (const float*)d_in[17];
    const float* b3v  = (const float*)d_in[18];
    const float* g1lw = (const float*)d_in[19];
    const float* g1lb = (const float*)d_in[20];
    const float* g1aw = (const float*)d_in[21];
    const float* g1ab = (const float*)d_in[22];
    const float* g2lw = (const float*)d_in[23];
    const float* g2lb = (const float*)d_in[24];
    const float* g2aw = (const float*)d_in[25];
    const float* g2ab = (const float*)d_in[26];
    const float* fcw  = (const float*)d_in[27];
    const float* fcb  = (const float*)d_in[28];
    const int*   EI   = (const int*)d_in[29];

    // runtime chunk size: largest of {64,32,16} that fits (chb*NPOS must be /256)
    size_t fixedB = 3000000;
    int chb = 16;
    if (ws_size >= (size_t)64 * 5680128 + fixedB)      chb = 64;
    else if (ws_size >= (size_t)32 * 5680128 + fixedB) chb = 32;
    int nchunks = Bn / chb;
    int mch = chb * NPOS;                  // positions per chunk (div by 256)

    char* p = (char*)d_ws;
    auto carve = [&](size_t bytes) {
        char* r = p;
        p += (bytes + 255) & ~(size_t)255;
        return r;
    };
    __hip_bfloat16* h1c = (__hip_bfloat16*)carve((size_t)chb * HP * HP * C1c * 2);
    __hip_bfloat16* h2c = (__hip_bfloat16*)carve((size_t)chb * HP * HP * C2c * 2);
    __hip_bfloat16* wm2 = (__hip_bfloat16*)carve((size_t)9 * C1c * 256 * 2);
    __hip_bfloat16* wm3 = (__hip_bfloat16*)carve((size_t)9 * C2c * 256 * 2);
    float* sb2  = (float*)carve(512 * 4);
    float* sb3  = (float*)carve(512 * 4);
    float* pool = (float*)carve(64 * 256 * 4);
    float* h0   = (float*)carve(64 * 256 * 4);
    float* hg1  = (float*)carve(64 * 256 * 4);
    float* hg2  = (float*)carve(64 * 256 * 4);
    float* ew1  = (float*)carve(256 * 4);
    float* ew2  = (float*)carve(256 * 4);

    // prep (independent of conv outputs); halos stay zero across chunks/replays
    halo_zero<C1c><<<dim3(chb * 340), dim3(C1c), 0, stream>>>(h1c);
    halo_zero<C2c><<<dim3(chb * 340), dim3(C2c), 0, stream>>>(h2c);
    prep_w<C1c><<<dim3(9 * C1c), dim3(256), 0, stream>>>(c2w, wm2);
    prep_w<C2c><<<dim3(9 * C2c), dim3(256), 0, stream>>>(c3w, wm3);
    prep_sb<<<dim3(1), dim3(256), 0, stream>>>(c2b, b2g, b2b, b2m, b2v, sb2);
    prep_sb<<<dim3(1), dim3(256), 0, stream>>>(c3b, b3g, b3b, b3m, b3v, sb3);
    zero_f32<<<dim3(64), dim3(256), 0, stream>>>(pool);

    // conv chain, chunked over batch (chb images per chunk)
    for (int ch = 0; ch < nchunks; ch++) {
        const float* xch = X + (size_t)ch * chb * 3 * NPOS;
        conv1_k<<<dim3(chb * Hs), dim3(C1c), 0, stream>>>(
            xch, c1w, c1b, b1g, b1b, b1m, b1v, h1c);
        conv_igemm<C1c, false><<<dim3(mch / 256), dim3(512), 0, stream>>>(
            h1c, wm2, sb2, h2c, nullptr);
        conv_igemm<C2c, true ><<<dim3(mch / 256), dim3(512), 0, stream>>>(
            h2c, wm3, sb3, nullptr, pool + (size_t)ch * chb * 256);
    }
    pool_div<<<dim3(64), dim3(256), 0, stream>>>(pool, h0);

    // GCN layers + fc
    gcn_attn<<<dim3(1), dim3(256), 0, stream>>>(h0, g1aw, g1ab, EI, ew1);
    gcn_agg<<<dim3(64), dim3(256), 0, stream>>>(h0, ew1, EI, g1lw, g1lb, hg1);
    gcn_attn<<<dim3(1), dim3(256), 0, stream>>>(hg1, g2aw, g2ab, EI, ew2);
    gcn_agg<<<dim3(64), dim3(256), 0, stream>>>(hg1, ew2, EI, g2lw, g2lb, hg2);
    fc_k<<<dim3(64), dim3(64), 0, stream>>>(hg2, fcw, fcb, (float*)d_out);
}